// Round 1
// baseline (1103.027 us; speedup 1.0000x reference)
//
#include <hip/hip_runtime.h>
#include <hip/hip_bf16.h>
#include <math.h>

#define NF 500
#define HID 64
#define NCLS 40

// cvec layout: [0,64) c1 slope for t>=0 ; [64,128) c1 slope for t<0 ;
//              [128,168) c2 slope for t>=0 ; [168,208) c2 slope for t<0

__global__ void prep_kernel(const float* __restrict__ m1a, const float* __restrict__ m1bw,
                            const float* __restrict__ m2a, const float* __restrict__ m2bw,
                            float* __restrict__ c) {
  int j = threadIdx.x;
  if (j < HID) {
    float sp = 0.f, sn = 0.f;
    for (int k = 0; k < HID; ++k) {
      float a = m1a[k];
      float ap = a > 0.f ? a : 0.2f * a;   // slope seen when t >= 0
      float an = a > 0.f ? 0.2f * a : a;   // slope seen when t < 0
      float w = m1bw[k * HID + j];
      sp = fmaf(ap, w, sp);
      sn = fmaf(an, w, sn);
    }
    c[j] = sp;
    c[HID + j] = sn;
  }
  if (j < NCLS) {
    float sp = 0.f, sn = 0.f;
    for (int k = 0; k < NCLS; ++k) {
      float a = m2a[k];
      float ap = a > 0.f ? a : 0.2f * a;
      float an = a > 0.f ? 0.2f * a : a;
      float w = m2bw[k * NCLS + j];
      sp = fmaf(ap, w, sp);
      sn = fmaf(an, w, sn);
    }
    c[128 + j] = sp;
    c[168 + j] = sn;
  }
}

__global__ void hist_kernel(const int* __restrict__ ei, int E,
                            int* __restrict__ deg_src, int* __restrict__ deg_dst) {
  int i = blockIdx.x * blockDim.x + threadIdx.x;
  if (i < E) {
    atomicAdd(&deg_src[ei[i]], 1);
    atomicAdd(&deg_dst[ei[E + i]], 1);
  }
}

// single-block exclusive scan of two arrays (degrees -> offsets), also copies to cursor arrays
__global__ void scan2_kernel(int* __restrict__ a, int* __restrict__ cura,
                             int* __restrict__ b, int* __restrict__ curb, int n) {
  __shared__ int wsum[16];
  __shared__ int carry_s;
  const int tid = threadIdx.x;
  const int lane = tid & 63;
  const int wv = tid >> 6;
  for (int pass = 0; pass < 2; ++pass) {
    int* arr = pass ? b : a;
    int* cur = pass ? curb : cura;
    if (tid == 0) carry_s = 0;
    __syncthreads();
    for (int base = 0; base < n; base += 1024) {
      int i = base + tid;
      int v = (i < n) ? arr[i] : 0;
      int x = v;
#pragma unroll
      for (int off = 1; off < 64; off <<= 1) {
        int y = __shfl_up(x, off);
        if (lane >= off) x += y;
      }
      if (lane == 63) wsum[wv] = x;
      __syncthreads();
      int woff = carry_s;
      for (int k = 0; k < wv; ++k) woff += wsum[k];
      int excl = woff + x - v;
      if (i < n) { arr[i] = excl; cur[i] = excl; }
      __syncthreads();
      if (tid == 0) {
        int tot = 0;
#pragma unroll
        for (int k = 0; k < 16; ++k) tot += wsum[k];
        carry_s += tot;
      }
      __syncthreads();
    }
    if (tid == 0) arr[n] = carry_s;
    __syncthreads();
  }
}

__global__ void scatter_kernel(const int* __restrict__ ei, const float* __restrict__ wmul, int E,
                               int* __restrict__ cur_src, int* __restrict__ cur_dst,
                               float* __restrict__ t_src, int* __restrict__ sd_src,
                               float* __restrict__ t_dst) {
  int e = blockIdx.x * blockDim.x + threadIdx.x;
  if (e < E) {
    int s = ei[e], d = ei[E + e];
    float t = wmul[e];
    int ps = atomicAdd(&cur_src[s], 1);
    t_src[ps] = t;
    int pd = atomicAdd(&cur_dst[d], 1);
    sd_src[pd] = s;
    t_dst[pd] = t;
  }
}

// h1 = x @ w1 + b1   [N,64], f32 register-tiled: 64 nodes x 64 ch per block, 4x4 per thread
__global__ __launch_bounds__(256) void gemm1_kernel(const float* __restrict__ x,
    const float* __restrict__ w1, const float* __restrict__ b1,
    float* __restrict__ h1, int N) {
  __shared__ float sx[32][68];   // transposed x tile: sx[k][node], padded
  __shared__ float sw[32][64];   // sw[k][ch]
  const int tid = threadIdx.x;
  const int tx = tid & 15;       // node quad
  const int ty = tid >> 4;       // channel quad
  const int n0 = blockIdx.x * 64;
  float acc[4][4] = {};
  for (int k0 = 0; k0 < NF; k0 += 32) {
#pragma unroll
    for (int l = 0; l < 2; ++l) {
      int idx = tid + l * 256;        // 0..511
      int nn = idx >> 3;              // node 0..63
      int kq = (idx & 7) * 4;         // k offset within tile
      int node = n0 + nn;
      int k = k0 + kq;
      float4 v = make_float4(0.f, 0.f, 0.f, 0.f);
      if (node < N && k < NF) v = *(const float4*)(x + (size_t)node * NF + k);
      sx[kq + 0][nn] = v.x;
      sx[kq + 1][nn] = v.y;
      sx[kq + 2][nn] = v.z;
      sx[kq + 3][nn] = v.w;
    }
#pragma unroll
    for (int l = 0; l < 8; ++l) {
      int idx = tid + l * 256;        // 0..2047
      int kk = idx >> 6;
      int ch = idx & 63;
      int k = k0 + kk;
      sw[kk][ch] = (k < NF) ? w1[(size_t)k * HID + ch] : 0.f;
    }
    __syncthreads();
#pragma unroll
    for (int kk = 0; kk < 32; ++kk) {
      float4 av = *(const float4*)&sx[kk][tx * 4];
      float4 bv = *(const float4*)&sw[kk][ty * 4];
      float aa[4] = {av.x, av.y, av.z, av.w};
      float bb[4] = {bv.x, bv.y, bv.z, bv.w};
#pragma unroll
      for (int i2 = 0; i2 < 4; ++i2)
#pragma unroll
        for (int j2 = 0; j2 < 4; ++j2)
          acc[i2][j2] = fmaf(aa[i2], bb[j2], acc[i2][j2]);
    }
    __syncthreads();
  }
  float4 bv = *(const float4*)(b1 + ty * 4);
  float bb[4] = {bv.x, bv.y, bv.z, bv.w};
#pragma unroll
  for (int i2 = 0; i2 < 4; ++i2) {
    int node = n0 + tx * 4 + i2;
    if (node < N) {
      float4 o = make_float4(acc[i2][0] + bb[0], acc[i2][1] + bb[1],
                             acc[i2][2] + bb[2], acc[i2][3] + bb[3]);
      *(float4*)(h1 + (size_t)node * HID + ty * 4) = o;
    }
  }
}

// per-source softmax denominators for both layers; g1 = h1/D1 in place; invD2 stored
__global__ void dpass_kernel(const int* __restrict__ off_src, const float* __restrict__ t_src,
                             const float* __restrict__ c, float* __restrict__ g1,
                             float* __restrict__ invD2, int N) {
  int node = blockIdx.x * 4 + (threadIdx.x >> 6);
  if (node >= N) return;
  int lane = threadIdx.x & 63;
  float c1p = c[lane], c1n = c[64 + lane];
  float c2p = lane < NCLS ? c[128 + lane] : 0.f;
  float c2n = lane < NCLS ? c[168 + lane] : 0.f;
  int b = off_src[node], e = off_src[node + 1];
  float d1 = 0.f, d2 = 0.f;
  for (int i = b; i < e; ++i) {
    float t = t_src[i];
    float s1 = t >= 0.f ? c1p : c1n;
    float s2 = t >= 0.f ? c2p : c2n;
    d1 += __expf(t * s1);
    d2 += __expf(t * s2);
  }
  float h = g1[(size_t)node * HID + lane];
  g1[(size_t)node * HID + lane] = d1 > 0.f ? h / d1 : 0.f;
  if (lane < NCLS) invD2[(size_t)node * NCLS + lane] = d2 > 0.f ? 1.f / d2 : 0.f;
}

// out1[d,:] = sum_e exp(t*c1) * g1[src,:]; a1 = elu(out1)
__global__ void aggB_kernel(const int* __restrict__ off_dst, const int* __restrict__ sd_src,
                            const float* __restrict__ t_dst, const float* __restrict__ c,
                            const float* __restrict__ g1, float* __restrict__ a1, int N) {
  int node = blockIdx.x * 4 + (threadIdx.x >> 6);
  if (node >= N) return;
  int lane = threadIdx.x & 63;
  float c1p = c[lane], c1n = c[64 + lane];
  int b = off_dst[node], e = off_dst[node + 1];
  float acc = 0.f;
  int i = b;
  for (; i + 1 < e; i += 2) {
    int s0 = sd_src[i], s1 = sd_src[i + 1];
    float t0 = t_dst[i], t1 = t_dst[i + 1];
    float ga = g1[(size_t)s0 * HID + lane];
    float gb = g1[(size_t)s1 * HID + lane];
    acc = fmaf(__expf(t0 * (t0 >= 0.f ? c1p : c1n)), ga, acc);
    acc = fmaf(__expf(t1 * (t1 >= 0.f ? c1p : c1n)), gb, acc);
  }
  if (i < e) {
    int s0 = sd_src[i];
    float t0 = t_dst[i];
    acc = fmaf(__expf(t0 * (t0 >= 0.f ? c1p : c1n)), g1[(size_t)s0 * HID + lane], acc);
  }
  a1[(size_t)node * HID + lane] = acc > 0.f ? acc : __expf(acc) - 1.f;  // elu
}

// g2 = (a1 @ w2 + b2) * invD2   [N,40]
__global__ __launch_bounds__(256) void gemm2_kernel(const float* __restrict__ a1,
    const float* __restrict__ w2, const float* __restrict__ b2,
    const float* __restrict__ invD2, float* __restrict__ g2, int N) {
  __shared__ float sa[32][65];
  __shared__ float sw[HID * NCLS];
  __shared__ float sb[NCLS];
  const int tid = threadIdx.x;
  const int n0 = blockIdx.x * 32;
  for (int i = tid; i < HID * NCLS; i += 256) sw[i] = w2[i];
  if (tid < NCLS) sb[tid] = b2[tid];
  for (int i = tid; i < 32 * HID; i += 256) {
    int r = i >> 6, col = i & 63;
    int node = n0 + r;
    sa[r][col] = node < N ? a1[(size_t)node * HID + col] : 0.f;
  }
  __syncthreads();
  const int r = tid >> 3;
  const int cg = (tid & 7) * 5;
  const int node = n0 + r;
  if (node >= N) return;
  float acc[5] = {};
  for (int k = 0; k < HID; ++k) {
    float a = sa[r][k];
#pragma unroll
    for (int u = 0; u < 5; ++u) acc[u] = fmaf(a, sw[k * NCLS + cg + u], acc[u]);
  }
#pragma unroll
  for (int u = 0; u < 5; ++u) {
    int ch = cg + u;
    g2[(size_t)node * NCLS + ch] = (acc[u] + sb[ch]) * invD2[(size_t)node * NCLS + ch];
  }
}

// out2[d,:] = sum_e exp(t*c2) * g2[src,:]; then row log_softmax -> d_out
__global__ void aggC_kernel(const int* __restrict__ off_dst, const int* __restrict__ sd_src,
                            const float* __restrict__ t_dst, const float* __restrict__ c,
                            const float* __restrict__ g2, float* __restrict__ out, int N) {
  int node = blockIdx.x * 4 + (threadIdx.x >> 6);
  if (node >= N) return;
  int lane = threadIdx.x & 63;
  bool act = lane < NCLS;
  float c2p = act ? c[128 + lane] : 0.f;
  float c2n = act ? c[168 + lane] : 0.f;
  int b = off_dst[node], e = off_dst[node + 1];
  float acc = 0.f;
  int i = b;
  for (; i + 1 < e; i += 2) {
    int s0 = sd_src[i], s1 = sd_src[i + 1];
    float t0 = t_dst[i], t1 = t_dst[i + 1];
    float ga = act ? g2[(size_t)s0 * NCLS + lane] : 0.f;
    float gb = act ? g2[(size_t)s1 * NCLS + lane] : 0.f;
    acc = fmaf(__expf(t0 * (t0 >= 0.f ? c2p : c2n)), ga, acc);
    acc = fmaf(__expf(t1 * (t1 >= 0.f ? c2p : c2n)), gb, acc);
  }
  if (i < e) {
    int s0 = sd_src[i];
    float t0 = t_dst[i];
    float ga = act ? g2[(size_t)s0 * NCLS + lane] : 0.f;
    acc = fmaf(__expf(t0 * (t0 >= 0.f ? c2p : c2n)), ga, acc);
  }
  // log_softmax over the 40 active lanes (butterfly over full wave with neutral pads)
  float v = act ? acc : -INFINITY;
  float m = v;
#pragma unroll
  for (int off = 32; off > 0; off >>= 1) m = fmaxf(m, __shfl_xor(m, off));
  float ex = act ? __expf(v - m) : 0.f;
  float s = ex;
#pragma unroll
  for (int off = 32; off > 0; off >>= 1) s += __shfl_xor(s, off);
  if (act) out[(size_t)node * NCLS + lane] = v - m - __logf(s);
}

extern "C" void kernel_launch(void* const* d_in, const int* in_sizes, int n_in,
                              void* d_out, int out_size, void* d_ws, size_t ws_size,
                              hipStream_t stream) {
  const float* x    = (const float*)d_in[0];
  const int*   ei   = (const int*)d_in[1];
  const float* wmul = (const float*)d_in[2];
  const float* w1   = (const float*)d_in[3];
  const float* b1   = (const float*)d_in[4];
  const float* m1a  = (const float*)d_in[5];
  const float* m1bw = (const float*)d_in[6];
  // d_in[7] (m1b_b) cancels in segment softmax — unused
  const float* w2   = (const float*)d_in[8];
  const float* b2   = (const float*)d_in[9];
  const float* m2a  = (const float*)d_in[10];
  const float* m2bw = (const float*)d_in[11];
  // d_in[12] (m2b_b) cancels — unused
  float* out = (float*)d_out;

  const int N = in_sizes[0] / NF;    // 100000
  const int E = in_sizes[2];         // 1600000 (w_mul element count)

  char* ws = (char*)d_ws;
  size_t off = 0;
  auto carve = [&](size_t bytes) -> void* {
    void* p = ws + off;
    off = (off + bytes + 255) & ~(size_t)255;
    return p;
  };
  int*   off_src = (int*)carve((size_t)2 * (N + 1) * sizeof(int));
  int*   off_dst = off_src + (N + 1);
  int*   cur_src = (int*)carve((size_t)2 * N * sizeof(int));
  int*   cur_dst = cur_src + N;
  float* cvec    = (float*)carve(208 * sizeof(float));
  float* t_src   = (float*)carve((size_t)E * sizeof(float));
  int*   sd_src  = (int*)carve((size_t)E * sizeof(int));
  float* t_dst   = (float*)carve((size_t)E * sizeof(float));
  float* h1      = (float*)carve((size_t)N * HID * sizeof(float));  // h1 -> g1 (in place) -> reused as g2
  float* invD2   = (float*)carve((size_t)N * NCLS * sizeof(float));
  float* a1      = (float*)carve((size_t)N * HID * sizeof(float));
  float* g2      = h1;  // g1 dead after aggB

  hipMemsetAsync(off_src, 0, (size_t)2 * (N + 1) * sizeof(int), stream);
  prep_kernel<<<1, 64, 0, stream>>>(m1a, m1bw, m2a, m2bw, cvec);
  hist_kernel<<<(E + 255) / 256, 256, 0, stream>>>(ei, E, off_src, off_dst);
  scan2_kernel<<<1, 1024, 0, stream>>>(off_src, cur_src, off_dst, cur_dst, N);
  scatter_kernel<<<(E + 255) / 256, 256, 0, stream>>>(ei, wmul, E, cur_src, cur_dst,
                                                      t_src, sd_src, t_dst);
  gemm1_kernel<<<(N + 63) / 64, 256, 0, stream>>>(x, w1, b1, h1, N);
  dpass_kernel<<<(N + 3) / 4, 256, 0, stream>>>(off_src, t_src, cvec, h1, invD2, N);
  aggB_kernel<<<(N + 3) / 4, 256, 0, stream>>>(off_dst, sd_src, t_dst, cvec, h1, a1, N);
  gemm2_kernel<<<(N + 31) / 32, 256, 0, stream>>>(a1, w2, b2, invD2, g2, N);
  aggC_kernel<<<(N + 3) / 4, 256, 0, stream>>>(off_dst, sd_src, t_dst, cvec, g2, out, N);
}

// Round 2
// 791.393 us; speedup vs baseline: 1.3938x; 1.3938x over previous
//
#include <hip/hip_runtime.h>
#include <hip/hip_bf16.h>
#include <math.h>

#define NF 500
#define HID 64
#define NCLS 40
#define NPART 8
#define SCHUNK 4096

// cvec layout: [0,64) c1 slope for t>=0 ; [64,128) c1 slope for t<0 ;
//              [128,168) c2 slope for t>=0 ; [168,208) c2 slope for t<0

__global__ void prep_kernel(const float* __restrict__ m1a, const float* __restrict__ m1bw,
                            const float* __restrict__ m2a, const float* __restrict__ m2bw,
                            float* __restrict__ c) {
  int j = threadIdx.x;
  if (j < HID) {
    float sp = 0.f, sn = 0.f;
    for (int k = 0; k < HID; ++k) {
      float a = m1a[k];
      float ap = a > 0.f ? a : 0.2f * a;   // slope seen when t >= 0
      float an = a > 0.f ? 0.2f * a : a;   // slope seen when t < 0
      float w = m1bw[k * HID + j];
      sp = fmaf(ap, w, sp);
      sn = fmaf(an, w, sn);
    }
    c[j] = sp;
    c[HID + j] = sn;
  }
  if (j < NCLS) {
    float sp = 0.f, sn = 0.f;
    for (int k = 0; k < NCLS; ++k) {
      float a = m2a[k];
      float ap = a > 0.f ? a : 0.2f * a;
      float an = a > 0.f ? 0.2f * a : a;
      float w = m2bw[k * NCLS + j];
      sp = fmaf(ap, w, sp);
      sn = fmaf(an, w, sn);
    }
    c[128 + j] = sp;
    c[168 + j] = sn;
  }
}

__global__ void hist_kernel(const int* __restrict__ ei, int E,
                            int* __restrict__ deg_src, int* __restrict__ deg_dst) {
  int i = blockIdx.x * blockDim.x + threadIdx.x;
  if (i < E) {
    atomicAdd(&deg_src[ei[i]], 1);
    atomicAdd(&deg_dst[ei[E + i]], 1);
  }
}

// ---- multi-block exclusive scan of two degree arrays (a,b of length n) ----
// A: per-chunk partial sums. blocks [0,nc) -> a, [nc,2nc) -> b.
__global__ __launch_bounds__(256) void scanA_kernel(const int* __restrict__ a,
    const int* __restrict__ b, int n, int nc, int* __restrict__ part) {
  const int bi = blockIdx.x;
  const int* arr = (bi < nc) ? a : b;
  const int ci = (bi < nc) ? bi : bi - nc;
  const int base = ci * SCHUNK;
  int s = 0;
  for (int u = threadIdx.x; u < SCHUNK; u += 256) {
    int i = base + u;
    if (i < n) s += arr[i];
  }
  __shared__ int ws[4];
#pragma unroll
  for (int off = 32; off > 0; off >>= 1) s += __shfl_down(s, off);
  if ((threadIdx.x & 63) == 0) ws[threadIdx.x >> 6] = s;
  __syncthreads();
  if (threadIdx.x == 0) part[bi] = ws[0] + ws[1] + ws[2] + ws[3];
}

// B: one wave scans the (<=64) partials of each array in place (exclusive); writes totals to a[n], b[n]
__global__ void scanB_kernel(int* __restrict__ part, int nc,
                             int* __restrict__ a, int* __restrict__ b, int n) {
  int lane = threadIdx.x;  // 64 threads
  for (int seg = 0; seg < 2; ++seg) {
    int v = (lane < nc) ? part[seg * nc + lane] : 0;
    int x = v;
#pragma unroll
    for (int off = 1; off < 64; off <<= 1) {
      int y = __shfl_up(x, off);
      if (lane >= off) x += y;
    }
    if (lane < nc) part[seg * nc + lane] = x - v;  // exclusive
    int tot = __shfl(x, 63);
    if (lane == 0) { if (seg == 0) a[n] = tot; else b[n] = tot; }
  }
}

// C: per-chunk scan + chunk offset; writes offsets into arr and cursor copy
__global__ __launch_bounds__(256) void scanC_kernel(int* __restrict__ a, int* __restrict__ cura,
    int* __restrict__ b, int* __restrict__ curb, int n, int nc, const int* __restrict__ part) {
  const int bi = blockIdx.x;
  int* arr; int* cur; int ci;
  if (bi < nc) { arr = a; cur = cura; ci = bi; }
  else         { arr = b; cur = curb; ci = bi - nc; }
  const int chunkoff = part[bi];
  const int base = ci * SCHUNK + threadIdx.x * 16;
  int v[16];
#pragma unroll
  for (int u = 0; u < 16; ++u) {
    int i = base + u;
    v[u] = (i < n) ? arr[i] : 0;
  }
  int tsum = 0;
#pragma unroll
  for (int u = 0; u < 16; ++u) tsum += v[u];
  const int lane = threadIdx.x & 63, wv = threadIdx.x >> 6;
  int x = tsum;
#pragma unroll
  for (int off = 1; off < 64; off <<= 1) {
    int y = __shfl_up(x, off);
    if (lane >= off) x += y;
  }
  __shared__ int ws[4];
  if (lane == 63) ws[wv] = x;
  __syncthreads();
  int woff = 0;
  for (int k = 0; k < wv; ++k) woff += ws[k];
  int toff = chunkoff + woff + x - tsum;  // exclusive offset of this thread's first element
#pragma unroll
  for (int u = 0; u < 16; ++u) {
    int i = base + u;
    if (i < n) { arr[i] = toff; cur[i] = toff; }
    toff += v[u];
  }
}

// ---- partition-localized CSR scatter ----
// grid = NPART * ceil(E/256); partition p = blockIdx&7 writes only nodes in [p*rng,(p+1)*rng)
// so (with round-robin block->XCD dispatch) each output line is filled from one XCD's L2.
__global__ __launch_bounds__(256) void scatter_kernel(const int* __restrict__ ei,
    const float* __restrict__ wmul, int E,
    int* __restrict__ cur_src, int* __restrict__ cur_dst,
    float* __restrict__ t_src, int2* __restrict__ pair, int N, int rng) {
  const int part = blockIdx.x & (NPART - 1);
  const int e = (blockIdx.x >> 3) * 256 + threadIdx.x;
  if (e >= E) return;
  const int lo = part * rng;
  const int hi = min(N, lo + rng);
  int s = ei[e], d = ei[E + e];
  bool ss = (s >= lo) && (s < hi);
  bool dd = (d >= lo) && (d < hi);
  if (!(ss || dd)) return;
  float t = wmul[e];
  if (ss) { int ps = atomicAdd(&cur_src[s], 1); t_src[ps] = t; }
  if (dd) { int pd = atomicAdd(&cur_dst[d], 1); pair[pd] = make_int2(s, __float_as_int(t)); }
}

// h1 = x @ w1 + b1   [N,64], f32 register-tiled: 64 nodes x 64 ch per block, 4x4 per thread
__global__ __launch_bounds__(256) void gemm1_kernel(const float* __restrict__ x,
    const float* __restrict__ w1, const float* __restrict__ b1,
    float* __restrict__ h1, int N) {
  __shared__ float sx[32][68];   // transposed x tile: sx[k][node], padded
  __shared__ float sw[32][64];   // sw[k][ch]
  const int tid = threadIdx.x;
  const int tx = tid & 15;       // node quad
  const int ty = tid >> 4;       // channel quad
  const int n0 = blockIdx.x * 64;
  float acc[4][4] = {};
  for (int k0 = 0; k0 < NF; k0 += 32) {
#pragma unroll
    for (int l = 0; l < 2; ++l) {
      int idx = tid + l * 256;        // 0..511
      int nn = idx >> 3;              // node 0..63
      int kq = (idx & 7) * 4;         // k offset within tile
      int node = n0 + nn;
      int k = k0 + kq;
      float4 v = make_float4(0.f, 0.f, 0.f, 0.f);
      if (node < N && k < NF) v = *(const float4*)(x + (size_t)node * NF + k);
      sx[kq + 0][nn] = v.x;
      sx[kq + 1][nn] = v.y;
      sx[kq + 2][nn] = v.z;
      sx[kq + 3][nn] = v.w;
    }
#pragma unroll
    for (int l = 0; l < 8; ++l) {
      int idx = tid + l * 256;        // 0..2047
      int kk = idx >> 6;
      int ch = idx & 63;
      int k = k0 + kk;
      sw[kk][ch] = (k < NF) ? w1[(size_t)k * HID + ch] : 0.f;
    }
    __syncthreads();
#pragma unroll
    for (int kk = 0; kk < 32; ++kk) {
      float4 av = *(const float4*)&sx[kk][tx * 4];
      float4 bv = *(const float4*)&sw[kk][ty * 4];
      float aa[4] = {av.x, av.y, av.z, av.w};
      float bb[4] = {bv.x, bv.y, bv.z, bv.w};
#pragma unroll
      for (int i2 = 0; i2 < 4; ++i2)
#pragma unroll
        for (int j2 = 0; j2 < 4; ++j2)
          acc[i2][j2] = fmaf(aa[i2], bb[j2], acc[i2][j2]);
    }
    __syncthreads();
  }
  float4 bv = *(const float4*)(b1 + ty * 4);
  float bb[4] = {bv.x, bv.y, bv.z, bv.w};
#pragma unroll
  for (int i2 = 0; i2 < 4; ++i2) {
    int node = n0 + tx * 4 + i2;
    if (node < N) {
      float4 o = make_float4(acc[i2][0] + bb[0], acc[i2][1] + bb[1],
                             acc[i2][2] + bb[2], acc[i2][3] + bb[3]);
      *(float4*)(h1 + (size_t)node * HID + ty * 4) = o;
    }
  }
}

// per-source softmax denominators for both layers; g1 = h1/D1 in place; invD2 stored
__global__ void dpass_kernel(const int* __restrict__ off_src, const float* __restrict__ t_src,
                             const float* __restrict__ c, float* __restrict__ g1,
                             float* __restrict__ invD2, int N) {
  int node = blockIdx.x * 4 + (threadIdx.x >> 6);
  if (node >= N) return;
  int lane = threadIdx.x & 63;
  float c1p = c[lane], c1n = c[64 + lane];
  float c2p = lane < NCLS ? c[128 + lane] : 0.f;
  float c2n = lane < NCLS ? c[168 + lane] : 0.f;
  int b = off_src[node], e = off_src[node + 1];
  float d1 = 0.f, d2 = 0.f;
  for (int i = b; i < e; ++i) {
    float t = t_src[i];
    float s1 = t >= 0.f ? c1p : c1n;
    float s2 = t >= 0.f ? c2p : c2n;
    d1 += __expf(t * s1);
    d2 += __expf(t * s2);
  }
  float h = g1[(size_t)node * HID + lane];
  g1[(size_t)node * HID + lane] = d1 > 0.f ? h / d1 : 0.f;
  if (lane < NCLS) invD2[(size_t)node * NCLS + lane] = d2 > 0.f ? 1.f / d2 : 0.f;
}

// out1[d,:] = sum_e exp(t*c1) * g1[src,:]; a1 = elu(out1)
__global__ void aggB_kernel(const int* __restrict__ off_dst, const int2* __restrict__ pair,
                            const float* __restrict__ c,
                            const float* __restrict__ g1, float* __restrict__ a1, int N) {
  int node = blockIdx.x * 4 + (threadIdx.x >> 6);
  if (node >= N) return;
  int lane = threadIdx.x & 63;
  float c1p = c[lane], c1n = c[64 + lane];
  int b = off_dst[node], e = off_dst[node + 1];
  float acc = 0.f;
  int i = b;
  for (; i + 1 < e; i += 2) {
    int2 p0 = pair[i], p1 = pair[i + 1];
    float t0 = __int_as_float(p0.y), t1 = __int_as_float(p1.y);
    float ga = g1[(size_t)p0.x * HID + lane];
    float gb = g1[(size_t)p1.x * HID + lane];
    acc = fmaf(__expf(t0 * (t0 >= 0.f ? c1p : c1n)), ga, acc);
    acc = fmaf(__expf(t1 * (t1 >= 0.f ? c1p : c1n)), gb, acc);
  }
  if (i < e) {
    int2 p0 = pair[i];
    float t0 = __int_as_float(p0.y);
    acc = fmaf(__expf(t0 * (t0 >= 0.f ? c1p : c1n)), g1[(size_t)p0.x * HID + lane], acc);
  }
  a1[(size_t)node * HID + lane] = acc > 0.f ? acc : __expf(acc) - 1.f;  // elu
}

// g2 = (a1 @ w2 + b2) * invD2   [N,40]
__global__ __launch_bounds__(256) void gemm2_kernel(const float* __restrict__ a1,
    const float* __restrict__ w2, const float* __restrict__ b2,
    const float* __restrict__ invD2, float* __restrict__ g2, int N) {
  __shared__ float sa[32][65];
  __shared__ float sw[HID * NCLS];
  __shared__ float sb[NCLS];
  const int tid = threadIdx.x;
  const int n0 = blockIdx.x * 32;
  for (int i = tid; i < HID * NCLS; i += 256) sw[i] = w2[i];
  if (tid < NCLS) sb[tid] = b2[tid];
  for (int i = tid; i < 32 * HID; i += 256) {
    int r = i >> 6, col = i & 63;
    int node = n0 + r;
    sa[r][col] = node < N ? a1[(size_t)node * HID + col] : 0.f;
  }
  __syncthreads();
  const int r = tid >> 3;
  const int cg = (tid & 7) * 5;
  const int node = n0 + r;
  if (node >= N) return;
  float acc[5] = {};
  for (int k = 0; k < HID; ++k) {
    float a = sa[r][k];
#pragma unroll
    for (int u = 0; u < 5; ++u) acc[u] = fmaf(a, sw[k * NCLS + cg + u], acc[u]);
  }
#pragma unroll
  for (int u = 0; u < 5; ++u) {
    int ch = cg + u;
    g2[(size_t)node * NCLS + ch] = (acc[u] + sb[ch]) * invD2[(size_t)node * NCLS + ch];
  }
}

// out2[d,:] = sum_e exp(t*c2) * g2[src,:]; then row log_softmax -> d_out
__global__ void aggC_kernel(const int* __restrict__ off_dst, const int2* __restrict__ pair,
                            const float* __restrict__ c,
                            const float* __restrict__ g2, float* __restrict__ out, int N) {
  int node = blockIdx.x * 4 + (threadIdx.x >> 6);
  if (node >= N) return;
  int lane = threadIdx.x & 63;
  bool act = lane < NCLS;
  float c2p = act ? c[128 + lane] : 0.f;
  float c2n = act ? c[168 + lane] : 0.f;
  int b = off_dst[node], e = off_dst[node + 1];
  float acc = 0.f;
  int i = b;
  for (; i + 1 < e; i += 2) {
    int2 p0 = pair[i], p1 = pair[i + 1];
    float t0 = __int_as_float(p0.y), t1 = __int_as_float(p1.y);
    float ga = act ? g2[(size_t)p0.x * NCLS + lane] : 0.f;
    float gb = act ? g2[(size_t)p1.x * NCLS + lane] : 0.f;
    acc = fmaf(__expf(t0 * (t0 >= 0.f ? c2p : c2n)), ga, acc);
    acc = fmaf(__expf(t1 * (t1 >= 0.f ? c2p : c2n)), gb, acc);
  }
  if (i < e) {
    int2 p0 = pair[i];
    float t0 = __int_as_float(p0.y);
    float ga = act ? g2[(size_t)p0.x * NCLS + lane] : 0.f;
    acc = fmaf(__expf(t0 * (t0 >= 0.f ? c2p : c2n)), ga, acc);
  }
  // log_softmax over the 40 active lanes (butterfly over full wave with neutral pads)
  float v = act ? acc : -INFINITY;
  float m = v;
#pragma unroll
  for (int off = 32; off > 0; off >>= 1) m = fmaxf(m, __shfl_xor(m, off));
  float ex = act ? __expf(v - m) : 0.f;
  float s = ex;
#pragma unroll
  for (int off = 32; off > 0; off >>= 1) s += __shfl_xor(s, off);
  if (act) out[(size_t)node * NCLS + lane] = v - m - __logf(s);
}

extern "C" void kernel_launch(void* const* d_in, const int* in_sizes, int n_in,
                              void* d_out, int out_size, void* d_ws, size_t ws_size,
                              hipStream_t stream) {
  const float* x    = (const float*)d_in[0];
  const int*   ei   = (const int*)d_in[1];
  const float* wmul = (const float*)d_in[2];
  const float* w1   = (const float*)d_in[3];
  const float* b1   = (const float*)d_in[4];
  const float* m1a  = (const float*)d_in[5];
  const float* m1bw = (const float*)d_in[6];
  // d_in[7] (m1b_b) cancels in segment softmax — unused
  const float* w2   = (const float*)d_in[8];
  const float* b2   = (const float*)d_in[9];
  const float* m2a  = (const float*)d_in[10];
  const float* m2bw = (const float*)d_in[11];
  // d_in[12] (m2b_b) cancels — unused
  float* out = (float*)d_out;

  const int N = in_sizes[0] / NF;    // 100000
  const int E = in_sizes[2];         // 1600000 (w_mul element count)

  char* ws = (char*)d_ws;
  size_t off = 0;
  auto carve = [&](size_t bytes) -> void* {
    void* p = ws + off;
    off = (off + bytes + 255) & ~(size_t)255;
    return p;
  };
  int*   off_src = (int*)carve((size_t)2 * (N + 1) * sizeof(int));
  int*   off_dst = off_src + (N + 1);
  int*   cur_src = (int*)carve((size_t)2 * N * sizeof(int));
  int*   cur_dst = cur_src + N;
  float* cvec    = (float*)carve(208 * sizeof(float));
  int*   psum    = (int*)carve(256 * sizeof(int));
  float* t_src   = (float*)carve((size_t)E * sizeof(float));
  int2*  pair    = (int2*)carve((size_t)E * sizeof(int2));
  float* h1      = (float*)carve((size_t)N * HID * sizeof(float));  // h1 -> g1 (in place) -> reused as g2
  float* invD2   = (float*)carve((size_t)N * NCLS * sizeof(float));
  float* a1      = (float*)carve((size_t)N * HID * sizeof(float));
  float* g2      = h1;  // g1 dead after aggB

  const int nc  = (N + SCHUNK - 1) / SCHUNK;              // chunks per array (<=64)
  const int rng = (N + NPART - 1) / NPART;                // nodes per scatter partition

  hipMemsetAsync(off_src, 0, (size_t)2 * (N + 1) * sizeof(int), stream);
  prep_kernel<<<1, 64, 0, stream>>>(m1a, m1bw, m2a, m2bw, cvec);
  hist_kernel<<<(E + 255) / 256, 256, 0, stream>>>(ei, E, off_src, off_dst);
  scanA_kernel<<<2 * nc, 256, 0, stream>>>(off_src, off_dst, N, nc, psum);
  scanB_kernel<<<1, 64, 0, stream>>>(psum, nc, off_src, off_dst, N);
  scanC_kernel<<<2 * nc, 256, 0, stream>>>(off_src, cur_src, off_dst, cur_dst, N, nc, psum);
  scatter_kernel<<<NPART * ((E + 255) / 256), 256, 0, stream>>>(ei, wmul, E, cur_src, cur_dst,
                                                                t_src, pair, N, rng);
  gemm1_kernel<<<(N + 63) / 64, 256, 0, stream>>>(x, w1, b1, h1, N);
  dpass_kernel<<<(N + 3) / 4, 256, 0, stream>>>(off_src, t_src, cvec, h1, invD2, N);
  aggB_kernel<<<(N + 3) / 4, 256, 0, stream>>>(off_dst, pair, cvec, h1, a1, N);
  gemm2_kernel<<<(N + 31) / 32, 256, 0, stream>>>(a1, w2, b2, invD2, g2, N);
  aggC_kernel<<<(N + 3) / 4, 256, 0, stream>>>(off_dst, pair, cvec, g2, out, N);
}

// Round 3
// 702.291 us; speedup vs baseline: 1.5706x; 1.1269x over previous
//
#include <hip/hip_runtime.h>
#include <hip/hip_bf16.h>
#include <math.h>

#define NF 500
#define HID 64
#define NCLS 40
#define NPART 8
#define SCHUNK 4096
#define KSTEPS 16   // ceil(500/32)

typedef __attribute__((ext_vector_type(8))) short short8v;
typedef __attribute__((ext_vector_type(4))) float f32x4v;

__device__ inline short f2bf(float f) {
  unsigned u = __float_as_uint(f);
  unsigned r = u + 0x7fff + ((u >> 16) & 1);   // RNE
  return (short)(r >> 16);
}

// cvec layout: [0,64) c1 slope for t>=0 ; [64,128) c1 slope for t<0 ;
//              [128,168) c2 slope for t>=0 ; [168,208) c2 slope for t<0

__global__ void prep_kernel(const float* __restrict__ m1a, const float* __restrict__ m1bw,
                            const float* __restrict__ m2a, const float* __restrict__ m2bw,
                            float* __restrict__ c) {
  int j = threadIdx.x;
  if (j < HID) {
    float sp = 0.f, sn = 0.f;
    for (int k = 0; k < HID; ++k) {
      float a = m1a[k];
      float ap = a > 0.f ? a : 0.2f * a;   // slope seen when t >= 0
      float an = a > 0.f ? 0.2f * a : a;   // slope seen when t < 0
      float w = m1bw[k * HID + j];
      sp = fmaf(ap, w, sp);
      sn = fmaf(an, w, sn);
    }
    c[j] = sp;
    c[HID + j] = sn;
  }
  if (j < NCLS) {
    float sp = 0.f, sn = 0.f;
    for (int k = 0; k < NCLS; ++k) {
      float a = m2a[k];
      float ap = a > 0.f ? a : 0.2f * a;
      float an = a > 0.f ? 0.2f * a : a;
      float w = m2bw[k * NCLS + j];
      sp = fmaf(ap, w, sp);
      sn = fmaf(an, w, sn);
    }
    c[128 + j] = sp;
    c[168 + j] = sn;
  }
}

// w1 -> bf16 in B-fragment-linear layout:
// wf[((s*4+f)*64 + l)*8 + j] = bf16(w1[k][ch]), k = s*32 + (l>>4)*8 + j, ch = f*16 + (l&15)
__global__ void wprep_kernel(const float* __restrict__ w1, short* __restrict__ wf) {
  int idx = blockIdx.x * 256 + threadIdx.x;   // 0..4095
  if (idx >= KSTEPS * 4 * 64) return;
  int l = idx & 63;
  int f = (idx >> 6) & 3;
  int s = idx >> 8;
  int ch = f * 16 + (l & 15);
  int kb = s * 32 + (l >> 4) * 8;
  short8v v;
#pragma unroll
  for (int j = 0; j < 8; ++j) {
    int k = kb + j;
    v[j] = (k < NF) ? f2bf(w1[(size_t)k * HID + ch]) : (short)0;
  }
  ((short8v*)wf)[idx] = v;
}

__global__ void hist_kernel(const int* __restrict__ ei, int E,
                            int* __restrict__ deg_src, int* __restrict__ deg_dst) {
  int i = blockIdx.x * blockDim.x + threadIdx.x;
  if (i < E) {
    atomicAdd(&deg_src[ei[i]], 1);
    atomicAdd(&deg_dst[ei[E + i]], 1);
  }
}

// ---- multi-block exclusive scan of two degree arrays (a,b of length n) ----
__global__ __launch_bounds__(256) void scanA_kernel(const int* __restrict__ a,
    const int* __restrict__ b, int n, int nc, int* __restrict__ part) {
  const int bi = blockIdx.x;
  const int* arr = (bi < nc) ? a : b;
  const int ci = (bi < nc) ? bi : bi - nc;
  const int base = ci * SCHUNK;
  int s = 0;
  for (int u = threadIdx.x; u < SCHUNK; u += 256) {
    int i = base + u;
    if (i < n) s += arr[i];
  }
  __shared__ int ws[4];
#pragma unroll
  for (int off = 32; off > 0; off >>= 1) s += __shfl_down(s, off);
  if ((threadIdx.x & 63) == 0) ws[threadIdx.x >> 6] = s;
  __syncthreads();
  if (threadIdx.x == 0) part[bi] = ws[0] + ws[1] + ws[2] + ws[3];
}

__global__ void scanB_kernel(int* __restrict__ part, int nc,
                             int* __restrict__ a, int* __restrict__ b, int n) {
  int lane = threadIdx.x;  // 64 threads
  for (int seg = 0; seg < 2; ++seg) {
    int v = (lane < nc) ? part[seg * nc + lane] : 0;
    int x = v;
#pragma unroll
    for (int off = 1; off < 64; off <<= 1) {
      int y = __shfl_up(x, off);
      if (lane >= off) x += y;
    }
    if (lane < nc) part[seg * nc + lane] = x - v;  // exclusive
    int tot = __shfl(x, 63);
    if (lane == 0) { if (seg == 0) a[n] = tot; else b[n] = tot; }
  }
}

__global__ __launch_bounds__(256) void scanC_kernel(int* __restrict__ a, int* __restrict__ cura,
    int* __restrict__ b, int* __restrict__ curb, int n, int nc, const int* __restrict__ part) {
  const int bi = blockIdx.x;
  int* arr; int* cur; int ci;
  if (bi < nc) { arr = a; cur = cura; ci = bi; }
  else         { arr = b; cur = curb; ci = bi - nc; }
  const int chunkoff = part[bi];
  const int base = ci * SCHUNK + threadIdx.x * 16;
  int v[16];
#pragma unroll
  for (int u = 0; u < 16; ++u) {
    int i = base + u;
    v[u] = (i < n) ? arr[i] : 0;
  }
  int tsum = 0;
#pragma unroll
  for (int u = 0; u < 16; ++u) tsum += v[u];
  const int lane = threadIdx.x & 63, wv = threadIdx.x >> 6;
  int x = tsum;
#pragma unroll
  for (int off = 1; off < 64; off <<= 1) {
    int y = __shfl_up(x, off);
    if (lane >= off) x += y;
  }
  __shared__ int ws[4];
  if (lane == 63) ws[wv] = x;
  __syncthreads();
  int woff = 0;
  for (int k = 0; k < wv; ++k) woff += ws[k];
  int toff = chunkoff + woff + x - tsum;
#pragma unroll
  for (int u = 0; u < 16; ++u) {
    int i = base + u;
    if (i < n) { arr[i] = toff; cur[i] = toff; }
    toff += v[u];
  }
}

// ---- partition-localized CSR scatter ----
__global__ __launch_bounds__(256) void scatter_kernel(const int* __restrict__ ei,
    const float* __restrict__ wmul, int E,
    int* __restrict__ cur_src, int* __restrict__ cur_dst,
    float* __restrict__ t_src, int2* __restrict__ pair, int N, int rng) {
  const int part = blockIdx.x & (NPART - 1);
  const int e = (blockIdx.x >> 3) * 256 + threadIdx.x;
  if (e >= E) return;
  const int lo = part * rng;
  const int hi = min(N, lo + rng);
  int s = ei[e], d = ei[E + e];
  bool ss = (s >= lo) && (s < hi);
  bool dd = (d >= lo) && (d < hi);
  if (!(ss || dd)) return;
  float t = wmul[e];
  if (ss) { int ps = atomicAdd(&cur_src[s], 1); t_src[ps] = t; }
  if (dd) { int pd = atomicAdd(&cur_dst[d], 1); pair[pd] = make_int2(s, __float_as_int(t)); }
}

// h1 = x @ w1 + b1 via bf16 MFMA. Block = 4 waves, 128 nodes; wave = 32 nodes x 64 ch.
// A-frags straight from global x (f32 -> bf16 in-register); B-frags from wf (coalesced, L2-hot).
__global__ __launch_bounds__(256, 4) void gemm1_mfma(const float* __restrict__ x,
    const short* __restrict__ wf, const float* __restrict__ b1,
    float* __restrict__ h1, int N) {
  const int tid = threadIdx.x;
  const int wv = tid >> 6, l = tid & 63;
  const int lr = l & 15, lk = l >> 4;
  const int n0 = blockIdx.x * 128 + wv * 32;
  int r0 = n0 + lr, r1 = r0 + 16;
  const float* p0 = x + (size_t)min(r0, N - 1) * NF + lk * 8;
  const float* p1 = x + (size_t)min(r1, N - 1) * NF + lk * 8;
  const short8v* wfv = (const short8v*)wf;

  f32x4v acc[2][4];
#pragma unroll
  for (int mi = 0; mi < 2; ++mi)
#pragma unroll
    for (int f = 0; f < 4; ++f) acc[mi][f] = (f32x4v){0.f, 0.f, 0.f, 0.f};

  const float4 z4 = make_float4(0.f, 0.f, 0.f, 0.f);
#pragma unroll
  for (int s = 0; s < KSTEPS; ++s) {
    float4 a0l, a0h, a1l, a1h;
    if (s < KSTEPS - 1) {
      a0l = *(const float4*)(p0 + s * 32);
      a0h = *(const float4*)(p0 + s * 32 + 4);
      a1l = *(const float4*)(p1 + s * 32);
      a1h = *(const float4*)(p1 + s * 32 + 4);
    } else {
      int k = (KSTEPS - 1) * 32 + lk * 8;        // 480,488,496,504
      if (k + 8 <= NF) {
        a0l = *(const float4*)(p0 + s * 32);
        a0h = *(const float4*)(p0 + s * 32 + 4);
        a1l = *(const float4*)(p1 + s * 32);
        a1h = *(const float4*)(p1 + s * 32 + 4);
      } else if (k + 4 <= NF) {
        a0l = *(const float4*)(p0 + s * 32); a0h = z4;
        a1l = *(const float4*)(p1 + s * 32); a1h = z4;
      } else {
        a0l = a0h = a1l = a1h = z4;
      }
    }
    short8v b[4];
#pragma unroll
    for (int f = 0; f < 4; ++f) b[f] = wfv[(s * 4 + f) * 64 + l];
    short8v a0, a1;
    a0[0] = f2bf(a0l.x); a0[1] = f2bf(a0l.y); a0[2] = f2bf(a0l.z); a0[3] = f2bf(a0l.w);
    a0[4] = f2bf(a0h.x); a0[5] = f2bf(a0h.y); a0[6] = f2bf(a0h.z); a0[7] = f2bf(a0h.w);
    a1[0] = f2bf(a1l.x); a1[1] = f2bf(a1l.y); a1[2] = f2bf(a1l.z); a1[3] = f2bf(a1l.w);
    a1[4] = f2bf(a1h.x); a1[5] = f2bf(a1h.y); a1[6] = f2bf(a1h.z); a1[7] = f2bf(a1h.w);
#pragma unroll
    for (int f = 0; f < 4; ++f) {
      acc[0][f] = __builtin_amdgcn_mfma_f32_16x16x32_bf16(a0, b[f], acc[0][f], 0, 0, 0);
      acc[1][f] = __builtin_amdgcn_mfma_f32_16x16x32_bf16(a1, b[f], acc[1][f], 0, 0, 0);
    }
  }

  // D layout: row = lk*4 + reg, col = lr (per m89)
#pragma unroll
  for (int mi = 0; mi < 2; ++mi) {
    int nbase = n0 + mi * 16 + lk * 4;
#pragma unroll
    for (int f = 0; f < 4; ++f) {
      int ch = f * 16 + lr;
      float bb = b1[ch];
#pragma unroll
      for (int reg = 0; reg < 4; ++reg) {
        int nd = nbase + reg;
        if (nd < N) h1[(size_t)nd * HID + ch] = acc[mi][f][reg] + bb;
      }
    }
  }
}

// per-source softmax denominators for both layers; g1 = h1/D1 in place; invD2 stored
__global__ void dpass_kernel(const int* __restrict__ off_src, const float* __restrict__ t_src,
                             const float* __restrict__ c, float* __restrict__ g1,
                             float* __restrict__ invD2, int N) {
  int node = blockIdx.x * 4 + (threadIdx.x >> 6);
  if (node >= N) return;
  int lane = threadIdx.x & 63;
  float c1p = c[lane], c1n = c[64 + lane];
  float c2p = lane < NCLS ? c[128 + lane] : 0.f;
  float c2n = lane < NCLS ? c[168 + lane] : 0.f;
  int b = off_src[node], e = off_src[node + 1];
  float d1 = 0.f, d2 = 0.f;
  for (int i = b; i < e; ++i) {
    float t = t_src[i];
    float s1 = t >= 0.f ? c1p : c1n;
    float s2 = t >= 0.f ? c2p : c2n;
    d1 += __expf(t * s1);
    d2 += __expf(t * s2);
  }
  float h = g1[(size_t)node * HID + lane];
  g1[(size_t)node * HID + lane] = d1 > 0.f ? h / d1 : 0.f;
  if (lane < NCLS) invD2[(size_t)node * NCLS + lane] = d2 > 0.f ? 1.f / d2 : 0.f;
}

// out1[d,:] = sum_e exp(t*c1) * g1[src,:]; a1 = elu(out1)
__global__ void aggB_kernel(const int* __restrict__ off_dst, const int2* __restrict__ pair,
                            const float* __restrict__ c,
                            const float* __restrict__ g1, float* __restrict__ a1, int N) {
  int node = blockIdx.x * 4 + (threadIdx.x >> 6);
  if (node >= N) return;
  int lane = threadIdx.x & 63;
  float c1p = c[lane], c1n = c[64 + lane];
  int b = off_dst[node], e = off_dst[node + 1];
  float acc = 0.f;
  int i = b;
  for (; i + 1 < e; i += 2) {
    int2 p0 = pair[i], p1 = pair[i + 1];
    float t0 = __int_as_float(p0.y), t1 = __int_as_float(p1.y);
    float ga = g1[(size_t)p0.x * HID + lane];
    float gb = g1[(size_t)p1.x * HID + lane];
    acc = fmaf(__expf(t0 * (t0 >= 0.f ? c1p : c1n)), ga, acc);
    acc = fmaf(__expf(t1 * (t1 >= 0.f ? c1p : c1n)), gb, acc);
  }
  if (i < e) {
    int2 p0 = pair[i];
    float t0 = __int_as_float(p0.y);
    acc = fmaf(__expf(t0 * (t0 >= 0.f ? c1p : c1n)), g1[(size_t)p0.x * HID + lane], acc);
  }
  a1[(size_t)node * HID + lane] = acc > 0.f ? acc : __expf(acc) - 1.f;  // elu
}

// g2 = (a1 @ w2 + b2) * invD2   [N,40]
__global__ __launch_bounds__(256) void gemm2_kernel(const float* __restrict__ a1,
    const float* __restrict__ w2, const float* __restrict__ b2,
    const float* __restrict__ invD2, float* __restrict__ g2, int N) {
  __shared__ float sa[32][65];
  __shared__ float sw[HID * NCLS];
  __shared__ float sb[NCLS];
  const int tid = threadIdx.x;
  const int n0 = blockIdx.x * 32;
  for (int i = tid; i < HID * NCLS; i += 256) sw[i] = w2[i];
  if (tid < NCLS) sb[tid] = b2[tid];
  for (int i = tid; i < 32 * HID; i += 256) {
    int r = i >> 6, col = i & 63;
    int node = n0 + r;
    sa[r][col] = node < N ? a1[(size_t)node * HID + col] : 0.f;
  }
  __syncthreads();
  const int r = tid >> 3;
  const int cg = (tid & 7) * 5;
  const int node = n0 + r;
  if (node >= N) return;
  float acc[5] = {};
  for (int k = 0; k < HID; ++k) {
    float a = sa[r][k];
#pragma unroll
    for (int u = 0; u < 5; ++u) acc[u] = fmaf(a, sw[k * NCLS + cg + u], acc[u]);
  }
#pragma unroll
  for (int u = 0; u < 5; ++u) {
    int ch = cg + u;
    g2[(size_t)node * NCLS + ch] = (acc[u] + sb[ch]) * invD2[(size_t)node * NCLS + ch];
  }
}

// out2[d,:] = sum_e exp(t*c2) * g2[src,:]; then row log_softmax -> d_out
__global__ void aggC_kernel(const int* __restrict__ off_dst, const int2* __restrict__ pair,
                            const float* __restrict__ c,
                            const float* __restrict__ g2, float* __restrict__ out, int N) {
  int node = blockIdx.x * 4 + (threadIdx.x >> 6);
  if (node >= N) return;
  int lane = threadIdx.x & 63;
  bool act = lane < NCLS;
  float c2p = act ? c[128 + lane] : 0.f;
  float c2n = act ? c[168 + lane] : 0.f;
  int b = off_dst[node], e = off_dst[node + 1];
  float acc = 0.f;
  int i = b;
  for (; i + 1 < e; i += 2) {
    int2 p0 = pair[i], p1 = pair[i + 1];
    float t0 = __int_as_float(p0.y), t1 = __int_as_float(p1.y);
    float ga = act ? g2[(size_t)p0.x * NCLS + lane] : 0.f;
    float gb = act ? g2[(size_t)p1.x * NCLS + lane] : 0.f;
    acc = fmaf(__expf(t0 * (t0 >= 0.f ? c2p : c2n)), ga, acc);
    acc = fmaf(__expf(t1 * (t1 >= 0.f ? c2p : c2n)), gb, acc);
  }
  if (i < e) {
    int2 p0 = pair[i];
    float t0 = __int_as_float(p0.y);
    float ga = act ? g2[(size_t)p0.x * NCLS + lane] : 0.f;
    acc = fmaf(__expf(t0 * (t0 >= 0.f ? c2p : c2n)), ga, acc);
  }
  float v = act ? acc : -INFINITY;
  float m = v;
#pragma unroll
  for (int off = 32; off > 0; off >>= 1) m = fmaxf(m, __shfl_xor(m, off));
  float ex = act ? __expf(v - m) : 0.f;
  float s = ex;
#pragma unroll
  for (int off = 32; off > 0; off >>= 1) s += __shfl_xor(s, off);
  if (act) out[(size_t)node * NCLS + lane] = v - m - __logf(s);
}

extern "C" void kernel_launch(void* const* d_in, const int* in_sizes, int n_in,
                              void* d_out, int out_size, void* d_ws, size_t ws_size,
                              hipStream_t stream) {
  const float* x    = (const float*)d_in[0];
  const int*   ei   = (const int*)d_in[1];
  const float* wmul = (const float*)d_in[2];
  const float* w1   = (const float*)d_in[3];
  const float* b1   = (const float*)d_in[4];
  const float* m1a  = (const float*)d_in[5];
  const float* m1bw = (const float*)d_in[6];
  const float* w2   = (const float*)d_in[8];
  const float* b2   = (const float*)d_in[9];
  const float* m2a  = (const float*)d_in[10];
  const float* m2bw = (const float*)d_in[11];
  float* out = (float*)d_out;

  const int N = in_sizes[0] / NF;    // 100000
  const int E = in_sizes[2];         // 1600000

  char* ws = (char*)d_ws;
  size_t off = 0;
  auto carve = [&](size_t bytes) -> void* {
    void* p = ws + off;
    off = (off + bytes + 255) & ~(size_t)255;
    return p;
  };
  int*   off_src = (int*)carve((size_t)2 * (N + 1) * sizeof(int));
  int*   off_dst = off_src + (N + 1);
  int*   cur_src = (int*)carve((size_t)2 * N * sizeof(int));
  int*   cur_dst = cur_src + N;
  float* cvec    = (float*)carve(208 * sizeof(float));
  int*   psum    = (int*)carve(256 * sizeof(int));
  short* wf      = (short*)carve((size_t)KSTEPS * 4 * 64 * 8 * sizeof(short));
  float* t_src   = (float*)carve((size_t)E * sizeof(float));
  int2*  pair    = (int2*)carve((size_t)E * sizeof(int2));
  float* h1      = (float*)carve((size_t)N * HID * sizeof(float));
  float* invD2   = (float*)carve((size_t)N * NCLS * sizeof(float));
  float* a1      = (float*)carve((size_t)N * HID * sizeof(float));
  float* g2      = h1;  // g1 dead after aggB

  const int nc  = (N + SCHUNK - 1) / SCHUNK;
  const int rng = (N + NPART - 1) / NPART;

  hipMemsetAsync(off_src, 0, (size_t)2 * (N + 1) * sizeof(int), stream);
  prep_kernel<<<1, 64, 0, stream>>>(m1a, m1bw, m2a, m2bw, cvec);
  wprep_kernel<<<16, 256, 0, stream>>>(w1, wf);
  hist_kernel<<<(E + 255) / 256, 256, 0, stream>>>(ei, E, off_src, off_dst);
  scanA_kernel<<<2 * nc, 256, 0, stream>>>(off_src, off_dst, N, nc, psum);
  scanB_kernel<<<1, 64, 0, stream>>>(psum, nc, off_src, off_dst, N);
  scanC_kernel<<<2 * nc, 256, 0, stream>>>(off_src, cur_src, off_dst, cur_dst, N, nc, psum);
  scatter_kernel<<<NPART * ((E + 255) / 256), 256, 0, stream>>>(ei, wmul, E, cur_src, cur_dst,
                                                                t_src, pair, N, rng);
  gemm1_mfma<<<(N + 127) / 128, 256, 0, stream>>>(x, wf, b1, h1, N);
  dpass_kernel<<<(N + 3) / 4, 256, 0, stream>>>(off_src, t_src, cvec, h1, invD2, N);
  aggB_kernel<<<(N + 3) / 4, 256, 0, stream>>>(off_dst, pair, cvec, h1, a1, N);
  gemm2_kernel<<<(N + 31) / 32, 256, 0, stream>>>(a1, w2, b2, invD2, g2, N);
  aggC_kernel<<<(N + 3) / 4, 256, 0, stream>>>(off_dst, pair, cvec, g2, out, N);
}